// Round 4
// baseline (597.716 us; speedup 1.0000x reference)
//
#include <hip/hip_runtime.h>
#include <hip/hip_bf16.h>

#define IN_DIM 256
#define HID    128
#define NSEG   320
#define MAXNORM 0.99999

#define G      8                    // nodes per group (= LDS accum slots)
#define NGRP   16384                // 131072 / 8
#define NPAN   32                   // src panels
#define PANSH  12                   // src>>12 -> 4096 rows = 1MB bf16 per panel
#define NKEY   (NGRP * NPAN)        // 524288 sort keys

typedef short bf16x8 __attribute__((ext_vector_type(8)));
typedef float f32x4  __attribute__((ext_vector_type(4)));

static __device__ __forceinline__ ushort f2b(float f) {
    uint u = __builtin_bit_cast(uint, f);
    uint r = 0x7FFFu + ((u >> 16) & 1u);      // round-to-nearest-even
    return (ushort)((u + r) >> 16);
}
static __device__ __forceinline__ float b2f_lo(uint v) {
    return __builtin_bit_cast(float, v << 16);
}
static __device__ __forceinline__ float b2f_hi(uint v) {
    return __builtin_bit_cast(float, v & 0xFFFF0000u);
}

// ---------------------------------------------------------------------------
// Edge sort by key = (dst>>3)*NPAN + (src>>PANSH): count -> scan -> fill
// ---------------------------------------------------------------------------
__global__ void count_edges_k(const int* __restrict__ src, const int* __restrict__ dst,
                              int* __restrict__ counts, int n) {
    int e = blockIdx.x * 256 + threadIdx.x;
    if (e < n) {
        int key = ((dst[e] >> 3) << 5) | (src[e] >> PANSH);
        atomicAdd(&counts[key], 1);
    }
}

// 1024 elements per block, 256 threads, int4 per thread
__global__ void scan_block_k(const int* __restrict__ in, int* __restrict__ out,
                             int* __restrict__ partials) {
    __shared__ int sh[256];
    int tid = threadIdx.x;
    int base = blockIdx.x * 1024 + tid * 4;
    int4 v = *(const int4*)&in[base];
    int s = v.x + v.y + v.z + v.w;
    sh[tid] = s;
    __syncthreads();
#pragma unroll
    for (int off = 1; off < 256; off <<= 1) {
        int t = (tid >= off) ? sh[tid - off] : 0;
        __syncthreads();
        sh[tid] += t;
        __syncthreads();
    }
    int excl = sh[tid] - s;
    int4 o;
    o.x = excl; o.y = excl + v.x; o.z = o.y + v.y; o.w = o.z + v.z;
    *(int4*)&out[base] = o;
    if (tid == 255) partials[blockIdx.x] = sh[255];
}

__global__ void scan_partials_k(int* __restrict__ partials, int n) {
    __shared__ int sh[1024];
    int tid = threadIdx.x;
    int v = (tid < n) ? partials[tid] : 0;
    sh[tid] = v;
    __syncthreads();
    for (int off = 1; off < blockDim.x; off <<= 1) {
        int t = (tid >= off) ? sh[tid - off] : 0;
        __syncthreads();
        sh[tid] += t;
        __syncthreads();
    }
    if (tid < n) partials[tid] = sh[tid] - v;
}

__global__ void add_base_k(int* __restrict__ offsets, const int* __restrict__ partials, int n) {
    int g = blockIdx.x * 256 + threadIdx.x;
    if (g < n) offsets[g] += partials[g >> 10];
}

// packed edge = src | ((dst&7)<<28)
__global__ void fill_edges_k(const int* __restrict__ src, const int* __restrict__ dst,
                             const int* __restrict__ offsets, int* __restrict__ cursor,
                             uint* __restrict__ packed, int n) {
    int e = blockIdx.x * 256 + threadIdx.x;
    if (e < n) {
        int s = src[e], d = dst[e];
        int key = ((d >> 3) << 5) | (s >> PANSH);
        int pos = atomicAdd(&cursor[key], 1);
        packed[offsets[key] + pos] = (uint)s | ((uint)(d & 7) << 28);
    }
}

// per-group edge ranges: goff[g] = offsets[g*NPAN], goff[NGRP] = E
__global__ void extract_goff_k(const int* __restrict__ offsets, int* __restrict__ goff, int E) {
    int g = blockIdx.x * 256 + threadIdx.x;
    if (g < NGRP) goff[g] = offsets[g << 5];
    if (g == NGRP) goff[g] = E;
}

// ---------------------------------------------------------------------------
// W pre-transpose+convert: W[K][128] f32 -> WT[128][K] bf16 (both weights)
// ---------------------------------------------------------------------------
__global__ void prep_wt_k(const float* __restrict__ w1, const float* __restrict__ w2,
                          ushort* __restrict__ w1t, ushort* __restrict__ w2t) {
    int id = blockIdx.x * 256 + threadIdx.x;
    if (id < 32768) {                      // W1: 256x128 -> 128x256
        int n = id >> 8, k = id & 255;
        w1t[n * 256 + k] = f2b(w1[k * 128 + n]);
    } else {                               // W2: 128x128 -> 128x128
        int id2 = id - 32768;
        int n = id2 >> 7, k = id2 & 127;
        w2t[n * 128 + k] = f2b(w2[k * 128 + n]);
    }
}

// ---------------------------------------------------------------------------
// bf16 MFMA GEMM: C[M][128](bf16) = A[M][K] @ B[K][128]   (unchanged, verified)
// ---------------------------------------------------------------------------
template<bool AF32>
__global__ __launch_bounds__(256) void gemm_k(const void* __restrict__ Ap,
                                              const ushort* __restrict__ BT,
                                              ushort* __restrict__ C, int K) {
    __shared__ __align__(16) char As[16384];   // [128][64] bf16, swizzled
    __shared__ __align__(16) char Bs[16384];   // [128(n)][64(k)] bf16, swizzled
    const int tid = threadIdx.x;
    const int lane = tid & 63;
    const int wid = tid >> 6;
    const int wr = wid >> 1, wc = wid & 1;
    const int row0 = blockIdx.x * 128;
    f32x4 acc[4][4] = {};

    for (int k0 = 0; k0 < K; k0 += 64) {
        if (AF32) {
            const float* A = (const float*)Ap;
#pragma unroll
            for (int it = 0; it < 8; ++it) {
                int id = tid + it * 256;
                int r = id >> 4, c4 = (id & 15) * 4;
                float4 v = *(const float4*)&A[(size_t)(row0 + r) * K + k0 + c4];
                ushort4 h;
                h.x = f2b(v.x); h.y = f2b(v.y); h.z = f2b(v.z); h.w = f2b(v.w);
                *(ushort4*)(As + ((r * 128 + c4 * 2) ^ ((r & 7) << 4))) = h;
            }
        } else {
            const ushort* A = (const ushort*)Ap;
#pragma unroll
            for (int it = 0; it < 4; ++it) {
                int id = tid + it * 256;
                int r = id >> 3, c8 = (id & 7) * 8;
                bf16x8 v = *(const bf16x8*)&A[(size_t)(row0 + r) * K + k0 + c8];
                *(bf16x8*)(As + ((r * 128 + c8 * 2) ^ ((r & 7) << 4))) = v;
            }
        }
#pragma unroll
        for (int it = 0; it < 4; ++it) {
            int id = tid + it * 256;
            int n = id >> 3, c8 = (id & 7) * 8;
            bf16x8 v = *(const bf16x8*)&BT[(size_t)n * K + k0 + c8];
            *(bf16x8*)(Bs + ((n * 128 + c8 * 2) ^ ((n & 7) << 4))) = v;
        }
        __syncthreads();
#pragma unroll
        for (int kc = 0; kc < 2; ++kc) {
            bf16x8 af[4], bfr[4];
            int kb = (kc * 32 + (lane >> 4) * 8) * 2;
#pragma unroll
            for (int i = 0; i < 4; ++i) {
                int r = wr * 64 + i * 16 + (lane & 15);
                af[i] = *(const bf16x8*)(As + ((r * 128 + kb) ^ ((r & 7) << 4)));
                int n = wc * 64 + i * 16 + (lane & 15);
                bfr[i] = *(const bf16x8*)(Bs + ((n * 128 + kb) ^ ((n & 7) << 4)));
            }
#pragma unroll
            for (int i = 0; i < 4; ++i)
#pragma unroll
                for (int j = 0; j < 4; ++j)
                    acc[i][j] = __builtin_amdgcn_mfma_f32_16x16x32_bf16(
                        af[i], bfr[j], acc[i][j], 0, 0, 0);
        }
        __syncthreads();
    }
#pragma unroll
    for (int i = 0; i < 4; ++i)
#pragma unroll
        for (int j = 0; j < 4; ++j)
#pragma unroll
            for (int r = 0; r < 4; ++r) {
                int row = row0 + wr * 64 + i * 16 + (lane >> 4) * 4 + r;
                int col = wc * 64 + j * 16 + (lane & 15);
                C[(size_t)row * 128 + col] = f2b(acc[i][j][r]);
            }
}

// ---------------------------------------------------------------------------
// Grouped, panel-ordered gather. Wave = 2 groups of 8 nodes (sequential
// sweeps). Edges sorted by (group, src_panel) -> XCD L2 holds the current
// panel. 64 packed edges vector-loaded, extracted via v_readlane; 16-deep
// row loads; LDS f32 accumulators (4KB/wave, no cross-wave sharing).
// ---------------------------------------------------------------------------
template<bool POOL>
__global__ __launch_bounds__(256, 8) void gather_grp_k(
    const uint* __restrict__ sup, const int* __restrict__ goff,
    const uint* __restrict__ packed, const float* __restrict__ bias,
    const int* __restrict__ seg_ids, uint* __restrict__ h1,
    float* __restrict__ sums, int* __restrict__ seg_cnt) {
    __shared__ float lds[4][G * 128];          // 16 KB/block
    const int wslot = threadIdx.x >> 6;
    const int lane  = threadIdx.x & 63;
    float* acc = &lds[wslot][0];
    const int wave = blockIdx.x * 4 + wslot;   // 0..8191
    float2 bv = *(const float2*)&bias[2 * lane];

    for (int sweep = 0; sweep < 2; ++sweep) {
        const int g = wave * 2 + sweep;        // group id, uniform
#pragma unroll
        for (int n = 0; n < G; ++n)
            *(float2*)&acc[n * 128 + 2 * lane] = float2{0.f, 0.f};

        int base = goff[g];
        int cnt  = goff[g + 1] - base;
        int j = 0;
        while (j < cnt) {
            int rem = cnt - j; if (rem > 64) rem = 64;
            uint pe = 0;
            if (lane < rem) pe = packed[base + j + lane];
            int t = 0;
            for (; t + 16 <= rem; t += 16) {
                uint r[16];
#pragma unroll
                for (int u = 0; u < 16; ++u) {
                    uint p = __builtin_amdgcn_readlane(pe, t + u);
                    uint s = p & 0xFFFFFFu;
                    r[u] = sup[(size_t)s * 64 + lane];
                }
#pragma unroll
                for (int u = 0; u < 16; ++u) {
                    uint p = __builtin_amdgcn_readlane(pe, t + u);
                    uint l = p >> 28;
                    float2 a = *(float2*)&acc[l * 128 + 2 * lane];
                    a.x += b2f_lo(r[u]); a.y += b2f_hi(r[u]);
                    *(float2*)&acc[l * 128 + 2 * lane] = a;
                }
            }
            for (; t < rem; ++t) {
                uint p = __builtin_amdgcn_readlane(pe, t);
                uint s = p & 0xFFFFFFu;
                uint l = p >> 28;
                uint v = sup[(size_t)s * 64 + lane];
                float2 a = *(float2*)&acc[l * 128 + 2 * lane];
                a.x += b2f_lo(v); a.y += b2f_hi(v);
                *(float2*)&acc[l * 128 + 2 * lane] = a;
            }
            j += rem;
        }
        // epilogue: 8 nodes of this group
#pragma unroll
        for (int n = 0; n < G; ++n) {
            int node = g * G + n;
            float2 a = *(float2*)&acc[n * 128 + 2 * lane];
            float hx = tanhf(a.x + bv.x), hy = tanhf(a.y + bv.y);
            if (!POOL) {
                h1[(size_t)node * 64 + lane] = ((uint)f2b(hy) << 16) | (uint)f2b(hx);
            } else {
                float ss = hx * hx + hy * hy;
#pragma unroll
                for (int o = 32; o > 0; o >>= 1) ss += __shfl_xor(ss, o);
                double rr = sqrt((double)fmaxf(ss, 1e-15f));
                double m = fmin(rr, MAXNORM);
                float f = (float)(atanh(m) / rr);   // logmap0(proj(h)) scale
                int seg = seg_ids[node];
                atomicAdd(&sums[seg * 128 + 2 * lane], hx * f);
                atomicAdd(&sums[seg * 128 + 2 * lane + 1], hy * f);
                if (lane == 0) atomicAdd(&seg_cnt[seg], 1);
            }
        }
    }
}

// segment mean -> expmap0 -> proj
__global__ __launch_bounds__(64) void finalize_k(const float* __restrict__ sums,
                                                 const int* __restrict__ seg_cnt,
                                                 float* __restrict__ out) {
    int seg = blockIdx.x;
    int lane = threadIdx.x;
    float c = fmaxf((float)seg_cnt[seg], 1.0f);
    float ux = sums[seg * 128 + 2 * lane] / c;
    float uy = sums[seg * 128 + 2 * lane + 1] / c;
    float ss = ux * ux + uy * uy;
#pragma unroll
    for (int o = 32; o > 0; o >>= 1) ss += __shfl_xor(ss, o);
    double r = sqrt((double)fmaxf(ss, 1e-15f));
    double t = tanh(r);
    double fac = t / r;
    if (t > MAXNORM) fac = MAXNORM / r;
    float f = (float)fac;
    out[seg * 128 + 2 * lane] = ux * f;
    out[seg * 128 + 2 * lane + 1] = uy * f;
}

// ---------------------------------------------------------------------------
extern "C" void kernel_launch(void* const* d_in, const int* in_sizes, int n_in,
                              void* d_out, int out_size, void* d_ws, size_t ws_size,
                              hipStream_t stream) {
    const float* x   = (const float*)d_in[0];
    const int* src   = (const int*)d_in[1];
    const int* dst   = (const int*)d_in[2];
    const int* segid = (const int*)d_in[3];
    const float* W1  = (const float*)d_in[4];
    const float* b1  = (const float*)d_in[5];
    const float* W2  = (const float*)d_in[6];
    const float* b2  = (const float*)d_in[7];
    float* out       = (float*)d_out;

    const int N = in_sizes[3];          // 131072
    const int E = in_sizes[1];          // 2097152

    char* ws = (char*)d_ws;
    // persistent buffers
    ushort* supA   = (ushort*)(ws);                      // N*128 bf16 = 32MB
    uint*   supA32 = (uint*)supA;
    uint*   h1u    = (uint*)(ws + 33554432);             // N*128 bf16 = 32MB
    ushort* h1     = (ushort*)h1u;
    uint* packed   = (uint*)(ws + 67108864);             // E uints = 8MB
    int* goff      = (int*)(ws + 75497472);              // (NGRP+1) ints
    float* sums    = (float*)(ws + 75563264);            // NSEG*128 f32
    int* seg_cnt   = (int*)(ws + 75727104);              // NSEG ints
    ushort* w1t    = (ushort*)(ws + 75728384);           // 128x256 bf16
    ushort* w2t    = (ushort*)(ws + 75793920);           // 128x128 bf16
    // sort scratch ALIASED into supA region (dead before gemm1 writes supA)
    int* counts    = (int*)(ws);                         // NKEY ints = 2MB
    int* offsets   = (int*)(ws + 2097152);               // NKEY ints = 2MB
    int* cursor    = (int*)(ws + 4194304);               // NKEY ints = 2MB
    int* partials  = (int*)(ws + 6291456);               // 512 ints

    hipMemsetAsync(counts, 0, (size_t)NKEY * 4, stream);
    hipMemsetAsync(cursor, 0, (size_t)NKEY * 4, stream);
    hipMemsetAsync(sums, 0, (size_t)NSEG * 128 * 4, stream);
    hipMemsetAsync(seg_cnt, 0, (size_t)NSEG * 4, stream);

    const int eblocks = (E + 255) / 256;

    prep_wt_k<<<192, 256, 0, stream>>>(W1, W2, w1t, w2t);

    // edge sort by (group, panel)
    count_edges_k<<<eblocks, 256, 0, stream>>>(src, dst, counts, E);
    scan_block_k<<<NKEY / 1024, 256, 0, stream>>>(counts, offsets, partials);
    scan_partials_k<<<1, NKEY / 1024, 0, stream>>>(partials, NKEY / 1024);
    add_base_k<<<NKEY / 256, 256, 0, stream>>>(offsets, partials, NKEY);
    fill_edges_k<<<eblocks, 256, 0, stream>>>(src, dst, offsets, cursor, packed, E);
    extract_goff_k<<<(NGRP + 256) / 256, 256, 0, stream>>>(offsets, goff, E);

    // layer 1
    gemm_k<true><<<N / 128, 256, 0, stream>>>(x, w1t, supA, IN_DIM);
    gather_grp_k<false><<<2048, 256, 0, stream>>>(supA32, goff, packed, b1, segid,
                                                  h1u, sums, seg_cnt);

    // layer 2
    gemm_k<false><<<N / 128, 256, 0, stream>>>(h1, w2t, supA, HID);
    gather_grp_k<true><<<2048, 256, 0, stream>>>(supA32, goff, packed, b2, segid,
                                                 h1u, sums, seg_cnt);

    finalize_k<<<NSEG, 64, 0, stream>>>(sums, seg_cnt, out);
}